// Round 13
// baseline (389.091 us; speedup 1.0000x reference)
//
#include <hip/hip_runtime.h>

using u16 = unsigned short;

typedef float  f32x4  __attribute__((ext_vector_type(4)));
typedef float  f32x16 __attribute__((ext_vector_type(16)));
typedef __bf16 bf16x8 __attribute__((ext_vector_type(8)));
typedef short  s16x8  __attribute__((ext_vector_type(8)));

#define DEVI __device__ __forceinline__

constexpr int TOK = 8192;    // N = B*L
constexpr int CIN = 1024;    // C
constexpr int C3  = 3072;    // 3C
constexpr int NH  = 16;
constexpr int HD  = 64;
constexpr int SL  = 2048;
constexpr int BH  = 64;      // B*H

constexpr float LOG2E = 1.4426950408889634f;

DEVI u16 f2bf(float x) {
  unsigned u = __builtin_bit_cast(unsigned, x);
  u += 0x7FFFu + ((u >> 16) & 1u);   // round-to-nearest-even
  return (u16)(u >> 16);
}

DEVI f32x4 mfma16(s16x8 a, s16x8 b, f32x4 c) {
  return __builtin_amdgcn_mfma_f32_16x16x32_bf16(
      __builtin_bit_cast(bf16x8, a), __builtin_bit_cast(bf16x8, b), c, 0, 0, 0);
}

DEVI f32x16 mfma32(s16x8 a, s16x8 b, f32x16 c) {
  return __builtin_amdgcn_mfma_f32_32x32x16_bf16(
      __builtin_bit_cast(bf16x8, a), __builtin_bit_cast(bf16x8, b), c, 0, 0, 0);
}

DEVI void gload_lds16(const void* g, void* l) {
  __builtin_amdgcn_global_load_lds(
      (const __attribute__((address_space(1))) unsigned int*)g,
      (__attribute__((address_space(3))) unsigned int*)l, 16, 0, 0);
}

DEVI unsigned cvtpk(float lo, float hi) {
  unsigned r;
  asm("v_cvt_pk_bf16_f32 %0, %1, %2" : "=v"(r) : "v"(lo), "v"(hi));
  return r;
}

DEVI void plswap(unsigned& a, unsigned& b) {
  asm("v_permlane32_swap_b32 %0, %1" : "+v"(a), "+v"(b));
}

// ---------------- merged preprocessing: cvt_x | transpose Wqkv | transpose Wout | bound ----
DEVI void do_transpose(const float* __restrict__ in, u16* __restrict__ out,
                       int R, int C, int blk, int tid, u16 (*t)[72]) {
  int rt = R >> 6;
  int tr = (blk % rt) << 6;
  int tc = (blk / rt) << 6;
#pragma unroll
  for (int k2 = 0; k2 < 16; k2++) {
    int idx = k2 * 256 + tid;
    int r = idx >> 6, c = idx & 63;
    t[r][c] = f2bf(in[(size_t)(tr + r) * C + tc + c]);
  }
  __syncthreads();
#pragma unroll
  for (int k2 = 0; k2 < 16; k2++) {
    int idx = k2 * 256 + tid;
    int r = idx >> 6, c = idx & 63;
    out[(size_t)(tc + r) * R + tr + c] = t[c][r];
  }
}

__global__ __launch_bounds__(256) void k_prep(
    const float* __restrict__ x, u16* __restrict__ xb,
    const float* __restrict__ Wqkv, u16* __restrict__ wqT,
    const float* __restrict__ Wout, u16* __restrict__ woT,
    const float* __restrict__ gq, const float* __restrict__ gk,
    float* __restrict__ bnd) {
  __shared__ u16 t[64][72];
  const int bid = blockIdx.x, tid = threadIdx.x;
  if (bid < 1024) {
    const int total = TOK * CIN / 4;
    for (int i = bid * 256 + tid; i < total; i += 1024 * 256) {
      float4 v = ((const float4*)x)[i];
      ushort4 o;
      o.x = f2bf(v.x); o.y = f2bf(v.y); o.z = f2bf(v.z); o.w = f2bf(v.w);
      ((ushort4*)xb)[i] = o;
    }
  } else if (bid < 1024 + 768) {
    do_transpose(Wqkv, wqT, 1024, 3072, bid - 1024, tid, t);
  } else if (bid < 1024 + 768 + 256) {
    do_transpose(Wout, woT, 1024, 1024, bid - 1792, tid, t);
  } else {
    const int h = tid >> 4, s = tid & 15;
    float mv = 0.f;
#pragma unroll
    for (int j = 0; j < 4; j++) {
      int d = s * 4 + j;
      mv = fmaxf(mv, fabsf(gq[h * 64 + d] * gk[h * 64 + d]));
    }
    mv = fmaxf(mv, __shfl_xor(mv, 1));
    mv = fmaxf(mv, __shfl_xor(mv, 2));
    mv = fmaxf(mv, __shfl_xor(mv, 4));
    mv = fmaxf(mv, __shfl_xor(mv, 8));
    if (s == 0) bnd[h] = 8.0f * LOG2E * mv;
  }
}

// ======== shared GEMM main loop: BM=BN=128, BK=32, 4 waves, ring-2, vmcnt(4) ========
// 2 LDS slots x 16 KB = 32 KB -> 5 blocks/CU (20 waves). Stage tile t+1 into
// slot (t+1)&1 (safe: issued after the barrier that ended t-1's reads of that
// slot); vmcnt(4) waits only for tile t's 4 loads, t+1's stay in flight.
#define STAGE4(SLOT, KT)                                                 \
  { char* Ld = L + (SLOT) * 16384;                                       \
    const size_t ko = (size_t)(KT) * 64;        /* 32 elems * 2B */      \
    gload_lds16(Ag + ko,          Ld + wq);                              \
    gload_lds16(Ag + ko + 131072, Ld + 4096 + wq);                       \
    gload_lds16(Bg + ko,          Ld + 8192 + wq);                       \
    gload_lds16(Bg + ko + 131072, Ld + 12288 + wq); }

#define KBODY2(KT, DOSTAGE, VMSTR)                                       \
  {                                                                      \
    if (DOSTAGE) STAGE4(((KT) + 1) & 1, (KT) + 1)                        \
    asm volatile("s_waitcnt " VMSTR ::: "memory");                       \
    __builtin_amdgcn_s_barrier();                                        \
    const char* Lb = L + ((KT) & 1) * 16384;                             \
    s16x8 af[4], bfr[4];                                                 \
    _Pragma("unroll")                                                    \
    for (int mf = 0; mf < 4; mf++)                                       \
      af[mf] = *(const s16x8*)(Lb + (wr + mf * 16 + l15) * 64 + g * 16); \
    _Pragma("unroll")                                                    \
    for (int nf = 0; nf < 4; nf++)                                       \
      bfr[nf] = *(const s16x8*)(Lb + 8192 + (wc + nf * 16 + l15) * 64 + g * 16); \
    __builtin_amdgcn_s_setprio(1);                                       \
    _Pragma("unroll")                                                    \
    for (int mf = 0; mf < 4; mf++)                                       \
      _Pragma("unroll")                                                  \
      for (int nf = 0; nf < 4; nf++)                                     \
        acc[mf][nf] = mfma16(af[mf], bfr[nf], acc[mf][nf]);              \
    __builtin_amdgcn_s_setprio(0);                                       \
    __builtin_amdgcn_s_barrier();                                        \
  }

DEVI void gemm_mainloop(const char* Ag, const char* Bg, char* L, int wq,
                        int wr, int wc, int l15, int g, f32x4 (&acc)[4][4]) {
  STAGE4(0, 0)
#pragma unroll
  for (int kt = 0; kt < 31; ++kt) KBODY2(kt, 1, "vmcnt(4)")
  KBODY2(31, 0, "vmcnt(0)")
}

// ---------------- GEMM1: qkv = xb @ wqkvT^T, fused bias+norm+repack ----------------
__global__ __launch_bounds__(256, 5) void k_gemm_qkv(
    const u16* __restrict__ A, const u16* __restrict__ Bt,
    const float* __restrict__ bias, const float* __restrict__ gq,
    const float* __restrict__ gk,
    u16* __restrict__ Qn, u16* __restrict__ Kn, u16* __restrict__ Vt) {
  __shared__ __align__(16) char Lsh[2][16384];
  int bid = blockIdx.x;
  bid = (bid & 7) * 192 + (bid >> 3);              // XCD swizzle, 1536 blocks
  const int bm = (bid / 24) * 128, bn = (bid % 24) * 128;
  const int tid = threadIdx.x, lane = tid & 63, w = tid >> 6;
  const int l15 = lane & 15, g = lane >> 4;
  const int wr = (w >> 1) * 64, wc = (w & 1) * 64;

  const int srow = tid >> 2, scol = (tid & 3) * 16;   // byte col
  const char* Ag = (const char*)A + (size_t)(bm + srow) * 2048 + scol;
  const char* Bg = (const char*)Bt + (size_t)(bn + srow) * 2048 + scol;
  const int wq = w << 10;

  f32x4 acc[4][4];
#pragma unroll
  for (int i = 0; i < 4; i++)
#pragma unroll
    for (int j = 0; j < 4; j++) acc[i][j] = f32x4{0.f, 0.f, 0.f, 0.f};

  gemm_mainloop(Ag, Bg, (char*)Lsh, wq, wr, wc, l15, g, acc);

  // epilogue: bias, per-head L2 norm for q/k (64 cols == one head), repack
  const int c0 = bn + wc;             // 64-aligned
  const int sec = c0 >> 10;           // 0=q 1=k 2=v
  const int head = (c0 & 1023) >> 6;
  float bv[4], gv[4];
#pragma unroll
  for (int nf = 0; nf < 4; nf++) {
    bv[nf] = bias[c0 + nf * 16 + l15];
    gv[nf] = 1.f;
    if (sec == 0) gv[nf] = gq[head * 64 + nf * 16 + l15];
    if (sec == 1) gv[nf] = gk[head * 64 + nf * 16 + l15];
  }
#pragma unroll
  for (int mf = 0; mf < 4; mf++) {
#pragma unroll
    for (int nf = 0; nf < 4; nf++)
#pragma unroll
      for (int r = 0; r < 4; r++) acc[mf][nf][r] += bv[nf];
    if (sec < 2) {
#pragma unroll
      for (int r = 0; r < 4; r++) {
        float ss = 0.f;
#pragma unroll
        for (int nf = 0; nf < 4; nf++) ss += acc[mf][nf][r] * acc[mf][nf][r];
        ss += __shfl_xor(ss, 1); ss += __shfl_xor(ss, 2);
        ss += __shfl_xor(ss, 4); ss += __shfl_xor(ss, 8);
        float nrm = fmaxf(sqrtf(ss), 1e-12f);
        float f = (sec == 0 ? LOG2E : 8.0f) / nrm;
#pragma unroll
        for (int nf = 0; nf < 4; nf++) acc[mf][nf][r] *= f;
      }
    }
    int rbase = bm + wr + mf * 16 + 4 * g;
#pragma unroll
    for (int r = 0; r < 4; r++) {
      int row = rbase + r;
      int b = row >> 11, tok = row & 2047;
      int bh = b * NH + head;
#pragma unroll
      for (int nf = 0; nf < 4; nf++) {
        int d = nf * 16 + l15;
        u16 val = f2bf(acc[mf][nf][r] * gv[nf]);
        if (sec == 0)      Qn[((size_t)bh * SL + tok) * HD + d] = val;
        else if (sec == 1) Kn[((size_t)bh * SL + tok) * HD + d] = val;
        else               Vt[((size_t)bh * HD + d) * SL + tok] = val;
      }
    }
  }
}

// ---------------- GEMM2: out = hm @ woutT^T + b_out (fp32 out) ----------------
__global__ __launch_bounds__(256, 5) void k_gemm_out(
    const u16* __restrict__ A, const u16* __restrict__ Bt,
    const float* __restrict__ bias, float* __restrict__ out) {
  __shared__ __align__(16) char Lsh[2][16384];
  int bid = blockIdx.x;
  bid = (bid & 7) * 64 + (bid >> 3);               // XCD swizzle, 512 blocks
  const int bm = (bid / 8) * 128, bn = (bid % 8) * 128;
  const int tid = threadIdx.x, lane = tid & 63, w = tid >> 6;
  const int l15 = lane & 15, g = lane >> 4;
  const int wr = (w >> 1) * 64, wc = (w & 1) * 64;

  const int srow = tid >> 2, scol = (tid & 3) * 16;
  const char* Ag = (const char*)A + (size_t)(bm + srow) * 2048 + scol;
  const char* Bg = (const char*)Bt + (size_t)(bn + srow) * 2048 + scol;
  const int wq = w << 10;

  f32x4 acc[4][4];
#pragma unroll
  for (int i = 0; i < 4; i++)
#pragma unroll
    for (int j = 0; j < 4; j++) acc[i][j] = f32x4{0.f, 0.f, 0.f, 0.f};

  gemm_mainloop(Ag, Bg, (char*)Lsh, wq, wr, wc, l15, g, acc);

  float bv[4];
#pragma unroll
  for (int nf = 0; nf < 4; nf++) bv[nf] = bias[bn + wc + nf * 16 + l15];
#pragma unroll
  for (int mf = 0; mf < 4; mf++)
#pragma unroll
    for (int r = 0; r < 4; r++) {
      int row = bm + wr + mf * 16 + 4 * g + r;
#pragma unroll
      for (int nf = 0; nf < 4; nf++)
        out[(size_t)row * CIN + bn + wc + nf * 16 + l15] = acc[mf][nf][r] + bv[nf];
    }
}

// ---------------- flash attention: 8 waves x 32 q, static-max softmax ----------------
__global__ __launch_bounds__(512) void k_attn(const u16* __restrict__ Qn,
                                              const u16* __restrict__ Kn,
                                              const u16* __restrict__ Vt,
                                              const float* __restrict__ bnd,
                                              u16* __restrict__ hm) {
  __shared__ __align__(16) char KL[2][8192];
  __shared__ __align__(16) char VL[2][8192];
  const int bh = blockIdx.x & 63, qb = blockIdx.x >> 6;   // qb 0..7
  const int tid = threadIdx.x, w = tid >> 6, lane = tid & 63;
  const int l31 = lane & 31, h = lane >> 5;
  const int qr0 = qb * 256 + w * 32;
  const float negM = -bnd[bh & 15];

  // ---- staging source addresses (per thread), pre-swizzled ----
  const int sr  = tid >> 3;                                  // 0..63 rows
  const int scb = ((tid & 7) << 4) ^ ((sr & 7) << 4);        // swizzled col-byte
  const char* kst = (const char*)(Kn + (size_t)bh * SL * HD) + (size_t)sr * 128 + scb;
  const char* vst = (const char*)(Vt + (size_t)bh * HD * SL) + (size_t)sr * 4096 + scb;
  char* kl0 = KL[0] + (w << 10);
  char* vl0 = VL[0] + (w << 10);
  char* kl1 = KL[1] + (w << 10);
  char* vl1 = VL[1] + (w << 10);

  // ---- Q B-fragments (once): lane holds Q[qr0+l31][ks*16 + 8h + j] ----
  const u16* Qb = Qn + ((size_t)bh * SL + qr0 + l31) * HD + 8 * h;
  s16x8 qf[4];
#pragma unroll
  for (int ks = 0; ks < 4; ks++) qf[ks] = *(const s16x8*)(Qb + ks * 16);

  // lane LDS read base byte offset (within a 32-row half tile)
  const int lb = l31 * 128 + ((h << 4) ^ ((l31 & 7) << 4));

  f32x16 o0, o1;
#pragma unroll
  for (int i = 0; i < 16; i++) { o0[i] = 0.f; o1[i] = 0.f; }
  float lr = 0.f;   // this lane's half-row partial sum

  // prologue: stage kb=0 into buf 0
  gload_lds16(kst, kl0);
  gload_lds16(vst, vl0);
  __syncthreads();

  for (int it = 0; it < 32; ++it) {
    const char* KB = (it & 1) ? KL[1] : KL[0];
    const char* VB = (it & 1) ? VL[1] : VL[0];
    if (it < 31) {                                   // prefetch next tile
      const size_t ko = (size_t)(it + 1) << 13;      // 64 rows * 128 B
      const size_t vo = (size_t)(it + 1) << 7;       // 64 toks * 2 B
      gload_lds16(kst + ko, (it & 1) ? kl0 : kl1);
      gload_lds16(vst + vo, (it & 1) ? vl0 : vl1);
    }

    // ---- QK^T (swapped), accumulator pre-loaded with -M ----
    f32x16 s0, s1;
#pragma unroll
    for (int i = 0; i < 16; i++) { s0[i] = negM; s1[i] = negM; }
    __builtin_amdgcn_s_setprio(1);
#pragma unroll
    for (int ks = 0; ks < 4; ks++) {
      const s16x8 ka  = *(const s16x8*)(KB + (lb ^ (ks << 5)));
      const s16x8 kb2 = *(const s16x8*)(KB + 4096 + (lb ^ (ks << 5)));
      s0 = mfma32(ka, qf[ks], s0);
      s1 = mfma32(kb2, qf[ks], s1);
    }
    __builtin_amdgcn_s_setprio(0);

    // ---- softmax numerators: p = exp2(s - M), fully parallel ----
#pragma unroll
    for (int i = 0; i < 16; i++) s0[i] = __builtin_amdgcn_exp2f(s0[i]);
#pragma unroll
    for (int i = 0; i < 16; i++) s1[i] = __builtin_amdgcn_exp2f(s1[i]);
    float sm8[8];
#pragma unroll
    for (int i = 0; i < 8; i++)
      sm8[i] = (s0[i] + s0[i + 8]) + (s1[i] + s1[i + 8]);
    lr += ((sm8[0] + sm8[1]) + (sm8[2] + sm8[3])) +
          ((sm8[4] + sm8[5]) + (sm8[6] + sm8[7]));

    // ---- P -> bf16 B-fragments (T12), PV ----
    union PBu { unsigned u[4]; s16x8 v; } pb;
#define MK_PB(SV, B)                              \
    {                                             \
      unsigned a0 = cvtpk(SV[B + 0], SV[B + 1]);  \
      unsigned c0 = cvtpk(SV[B + 4], SV[B + 5]);  \
      plswap(a0, c0);                             \
      unsigned a1 = cvtpk(SV[B + 2], SV[B + 3]);  \
      unsigned c1 = cvtpk(SV[B + 6], SV[B + 7]);  \
      plswap(a1, c1);                             \
      pb.u[0] = a0; pb.u[1] = a1; pb.u[2] = c0; pb.u[3] = c1; \
    }
#define PV_STEP(KS)                                            \
    {                                                          \
      const s16x8 va = *(const s16x8*)(VB + (lb ^ (KS << 5))); \
      const s16x8 vb = *(const s16x8*)(VB + 4096 + (lb ^ (KS << 5))); \
      __builtin_amdgcn_s_setprio(1);                           \
      o0 = mfma32(va, pb.v, o0);                               \
      o1 = mfma32(vb, pb.v, o1);                               \
      __builtin_amdgcn_s_setprio(0);                           \
    }
    MK_PB(s0, 0) PV_STEP(0)
    MK_PB(s0, 8) PV_STEP(1)
    MK_PB(s1, 0) PV_STEP(2)
    MK_PB(s1, 8) PV_STEP(3)
#undef MK_PB
#undef PV_STEP

    __syncthreads();   // drains vmcnt: next buffer staged; this buffer free
  }

  // ---- epilogue: combine half-row sums, normalize, store ----
  const float ltot = lr + __shfl_xor(lr, 32);
  const float inv = 1.f / ltot;
  const int bq = bh >> 4, hh = bh & 15;
  u16* hb = hm + ((size_t)bq * SL + qr0 + l31) * CIN + hh * HD;
#pragma unroll
  for (int rg = 0; rg < 4; rg++) {
    const int d0 = 8 * rg + 4 * h;
    unsigned lo = cvtpk(o0[4 * rg + 0] * inv, o0[4 * rg + 1] * inv);
    unsigned hi = cvtpk(o0[4 * rg + 2] * inv, o0[4 * rg + 3] * inv);
    *(unsigned long long*)(hb + d0) =
        (unsigned long long)lo | ((unsigned long long)hi << 32);
    unsigned lo1 = cvtpk(o1[4 * rg + 0] * inv, o1[4 * rg + 1] * inv);
    unsigned hi1 = cvtpk(o1[4 * rg + 2] * inv, o1[4 * rg + 3] * inv);
    *(unsigned long long*)(hb + 32 + d0) =
        (unsigned long long)lo1 | ((unsigned long long)hi1 << 32);
  }
}

extern "C" void kernel_launch(void* const* d_in, const int* in_sizes, int n_in,
                              void* d_out, int out_size, void* d_ws, size_t ws_size,
                              hipStream_t stream) {
  const float* x    = (const float*)d_in[0];
  const float* Wqkv = (const float*)d_in[1];
  const float* bqkv = (const float*)d_in[2];
  const float* gq   = (const float*)d_in[3];
  const float* gk   = (const float*)d_in[4];
  const float* Wout = (const float*)d_in[5];
  const float* bout = (const float*)d_in[6];
  float* out = (float*)d_out;

  char* ws = (char*)d_ws;
  u16* xb  = (u16*)(ws);                       // 16,777,216 B
  u16* wqT = (u16*)(ws + 16777216);            //  6,291,456 B
  u16* woT = (u16*)(ws + 23068672);            //  2,097,152 B
  u16* Qn  = (u16*)(ws + 25165824);            // 16,777,216 B
  u16* Kn  = (u16*)(ws + 41943040);            // 16,777,216 B
  u16* Vt  = (u16*)(ws + 58720256);            // 16,777,216 B
  u16* hm  = (u16*)(ws + 75497472);            // 16,777,216 B  (end: 92,274,688)
  float* bnd = (float*)(ws + 92274688);        // 64 B

  k_prep<<<2049, 256, 0, stream>>>(x, xb, Wqkv, wqT, Wout, woT, gq, gk, bnd);
  k_gemm_qkv<<<(TOK / 128) * (C3 / 128), 256, 0, stream>>>(xb, wqT, bqkv, gq, gk, Qn, Kn, Vt);
  k_attn<<<BH * (SL / 256), 512, 0, stream>>>(Qn, Kn, Vt, bnd, hm);
  k_gemm_out<<<(TOK / 128) * (CIN / 128), 256, 0, stream>>>(hm, woT, bout, out);
}

// Round 14
// 199.525 us; speedup vs baseline: 1.9501x; 1.9501x over previous
//
#include <hip/hip_runtime.h>

using u16 = unsigned short;

typedef float  f32x4  __attribute__((ext_vector_type(4)));
typedef float  f32x16 __attribute__((ext_vector_type(16)));
typedef __bf16 bf16x8 __attribute__((ext_vector_type(8)));
typedef short  s16x8  __attribute__((ext_vector_type(8)));

#define DEVI __device__ __forceinline__

constexpr int TOK = 8192;    // N = B*L
constexpr int CIN = 1024;    // C
constexpr int C3  = 3072;    // 3C
constexpr int NH  = 16;
constexpr int HD  = 64;
constexpr int SL  = 2048;
constexpr int BH  = 64;      // B*H

constexpr float LOG2E = 1.4426950408889634f;

DEVI u16 f2bf(float x) {
  unsigned u = __builtin_bit_cast(unsigned, x);
  u += 0x7FFFu + ((u >> 16) & 1u);   // round-to-nearest-even
  return (u16)(u >> 16);
}

DEVI f32x4 mfma16(s16x8 a, s16x8 b, f32x4 c) {
  return __builtin_amdgcn_mfma_f32_16x16x32_bf16(
      __builtin_bit_cast(bf16x8, a), __builtin_bit_cast(bf16x8, b), c, 0, 0, 0);
}

DEVI f32x16 mfma32(s16x8 a, s16x8 b, f32x16 c) {
  return __builtin_amdgcn_mfma_f32_32x32x16_bf16(
      __builtin_bit_cast(bf16x8, a), __builtin_bit_cast(bf16x8, b), c, 0, 0, 0);
}

DEVI void gload_lds16(const void* g, void* l) {
  __builtin_amdgcn_global_load_lds(
      (const __attribute__((address_space(1))) unsigned int*)g,
      (__attribute__((address_space(3))) unsigned int*)l, 16, 0, 0);
}

DEVI unsigned cvtpk(float lo, float hi) {
  unsigned r;
  asm("v_cvt_pk_bf16_f32 %0, %1, %2" : "=v"(r) : "v"(lo), "v"(hi));
  return r;
}

DEVI void plswap(unsigned& a, unsigned& b) {
  asm("v_permlane32_swap_b32 %0, %1" : "+v"(a), "+v"(b));
}

// ---------------- merged preprocessing: cvt_x | transpose Wqkv | transpose Wout | bound ----
DEVI void do_transpose(const float* __restrict__ in, u16* __restrict__ out,
                       int R, int C, int blk, int tid, u16 (*t)[72]) {
  int rt = R >> 6;
  int tr = (blk % rt) << 6;
  int tc = (blk / rt) << 6;
#pragma unroll
  for (int k2 = 0; k2 < 16; k2++) {
    int idx = k2 * 256 + tid;
    int r = idx >> 6, c = idx & 63;
    t[r][c] = f2bf(in[(size_t)(tr + r) * C + tc + c]);
  }
  __syncthreads();
#pragma unroll
  for (int k2 = 0; k2 < 16; k2++) {
    int idx = k2 * 256 + tid;
    int r = idx >> 6, c = idx & 63;
    out[(size_t)(tc + r) * R + tr + c] = t[c][r];
  }
}

__global__ __launch_bounds__(256) void k_prep(
    const float* __restrict__ x, u16* __restrict__ xb,
    const float* __restrict__ Wqkv, u16* __restrict__ wqT,
    const float* __restrict__ Wout, u16* __restrict__ woT,
    const float* __restrict__ gq, const float* __restrict__ gk,
    float* __restrict__ bnd) {
  __shared__ u16 t[64][72];
  const int bid = blockIdx.x, tid = threadIdx.x;
  if (bid < 1024) {
    const int total = TOK * CIN / 4;
    for (int i = bid * 256 + tid; i < total; i += 1024 * 256) {
      float4 v = ((const float4*)x)[i];
      ushort4 o;
      o.x = f2bf(v.x); o.y = f2bf(v.y); o.z = f2bf(v.z); o.w = f2bf(v.w);
      ((ushort4*)xb)[i] = o;
    }
  } else if (bid < 1024 + 768) {
    do_transpose(Wqkv, wqT, 1024, 3072, bid - 1024, tid, t);
  } else if (bid < 1024 + 768 + 256) {
    do_transpose(Wout, woT, 1024, 1024, bid - 1792, tid, t);
  } else {
    const int h = tid >> 4, s = tid & 15;
    float mv = 0.f;
#pragma unroll
    for (int j = 0; j < 4; j++) {
      int d = s * 4 + j;
      mv = fmaxf(mv, fabsf(gq[h * 64 + d] * gk[h * 64 + d]));
    }
    mv = fmaxf(mv, __shfl_xor(mv, 1));
    mv = fmaxf(mv, __shfl_xor(mv, 2));
    mv = fmaxf(mv, __shfl_xor(mv, 4));
    mv = fmaxf(mv, __shfl_xor(mv, 8));
    if (s == 0) bnd[h] = 8.0f * LOG2E * mv;
  }
}

// ======== shared GEMM main loop: BM=256 BN=128 BK=64, ring-3, counted vmcnt ========
// (R10 configuration: 1 block/CU, write-combining-safe, best measured)
#define STAGE6(BUF, KT)                                                  \
  { char* Ld = L + (BUF) * 49152;                                        \
    const size_t ko = (size_t)(KT) * 128;                                \
    gload_lds16(Ab + ko,          Ld + wb);                              \
    gload_lds16(Ab + ko + 131072, Ld + 8192 + wb);                       \
    gload_lds16(Ab + ko + 262144, Ld + 16384 + wb);                      \
    gload_lds16(Ab + ko + 393216, Ld + 24576 + wb);                      \
    gload_lds16(Bb + ko,          Ld + 32768 + wb);                      \
    gload_lds16(Bb + ko + 131072, Ld + 40960 + wb); }

#define KBODY(KT, DOSTAGE, VMSTR)                                        \
  {                                                                      \
    if (DOSTAGE) STAGE6(((KT) + 2) % 3, (KT) + 2)                        \
    asm volatile("s_waitcnt " VMSTR ::: "memory");                       \
    __builtin_amdgcn_s_barrier();                                        \
    const char* Lb = L + ((KT) % 3) * 49152;                             \
    s16x8 af[4][2], bfr[4][2];                                           \
    _Pragma("unroll")                                                    \
    for (int mf = 0; mf < 4; mf++) {                                     \
      af[mf][0] = *(const s16x8*)(Lb + aoff + mf * 2048 + cx0);          \
      af[mf][1] = *(const s16x8*)(Lb + aoff + mf * 2048 + (cx0 ^ 64));   \
    }                                                                    \
    _Pragma("unroll")                                                    \
    for (int nf = 0; nf < 4; nf++) {                                     \
      bfr[nf][0] = *(const s16x8*)(Lb + boff + nf * 2048 + cx0);         \
      bfr[nf][1] = *(const s16x8*)(Lb + boff + nf * 2048 + (cx0 ^ 64));  \
    }                                                                    \
    __builtin_amdgcn_s_setprio(1);                                       \
    _Pragma("unroll")                                                    \
    for (int ks = 0; ks < 2; ks++)                                       \
      _Pragma("unroll")                                                  \
      for (int mf = 0; mf < 4; mf++)                                     \
        _Pragma("unroll")                                                \
        for (int nf = 0; nf < 4; nf++)                                   \
          acc[mf][nf] = mfma16(af[mf][ks], bfr[nf][ks], acc[mf][nf]);    \
    __builtin_amdgcn_s_setprio(0);                                       \
    __builtin_amdgcn_s_barrier();                                        \
  }

DEVI void gemm_mainloop(const char* Ab, const char* Bb, char* L,
                        int wb, int aoff, int boff, int cx0,
                        f32x4 (&acc)[4][4]) {
  STAGE6(0, 0)
  STAGE6(1, 1)
#pragma unroll
  for (int kt = 0; kt < 14; ++kt) KBODY(kt, 1, "vmcnt(12)")
  KBODY(14, 0, "vmcnt(6)")
  KBODY(15, 0, "vmcnt(0)")
}

// ---------------- GEMM1: qkv = xb @ wqkvT^T, fused bias+norm+repack ----------------
__global__ __launch_bounds__(512, 2) void k_gemm_qkv(
    const u16* __restrict__ A, const u16* __restrict__ Bt,
    const float* __restrict__ bias, const float* __restrict__ gq,
    const float* __restrict__ gk,
    u16* __restrict__ Qn, u16* __restrict__ Kn, u16* __restrict__ Vt) {
  __shared__ __align__(16) char Lsh[3][49152];
  int bid = blockIdx.x;
  bid = (bid & 7) * 96 + (bid >> 3);               // XCD swizzle, 768 blocks
  const int bm = (bid / 24) * 256, bn = (bid % 24) * 128;
  const int tid = threadIdx.x, lane = tid & 63, w = tid >> 6;
  const int l15 = lane & 15, g = lane >> 4;
  const int wr4 = w >> 1, wc2 = w & 1;

  const int rA  = tid >> 3;
  const int scb = ((tid & 7) << 4) ^ ((rA & 7) << 4);
  const char* Ab = (const char*)A + (size_t)(bm + rA) * 2048 + scb;
  const char* Bb = (const char*)Bt + (size_t)(bn + rA) * 2048 + scb;
  const int wb   = w << 10;
  const int aoff = (wr4 * 64 + l15) * 128;
  const int boff = 32768 + (wc2 * 64 + l15) * 128;
  const int cx0  = (g ^ (l15 & 7)) << 4;

  f32x4 acc[4][4];
#pragma unroll
  for (int i = 0; i < 4; i++)
#pragma unroll
    for (int j = 0; j < 4; j++) acc[i][j] = f32x4{0.f, 0.f, 0.f, 0.f};

  gemm_mainloop(Ab, Bb, (char*)Lsh, wb, aoff, boff, cx0, acc);

  // epilogue: bias, per-head L2 norm for q/k (64 cols == one head), repack
  const int c0 = bn + wc2 * 64;       // 64-aligned
  const int sec = c0 >> 10;           // 0=q 1=k 2=v
  const int head = (c0 & 1023) >> 6;
  float bv[4], gv[4];
#pragma unroll
  for (int nf = 0; nf < 4; nf++) {
    bv[nf] = bias[c0 + nf * 16 + l15];
    gv[nf] = 1.f;
    if (sec == 0) gv[nf] = gq[head * 64 + nf * 16 + l15];
    if (sec == 1) gv[nf] = gk[head * 64 + nf * 16 + l15];
  }
#pragma unroll
  for (int mf = 0; mf < 4; mf++) {
#pragma unroll
    for (int nf = 0; nf < 4; nf++)
#pragma unroll
      for (int r = 0; r < 4; r++) acc[mf][nf][r] += bv[nf];
    if (sec < 2) {
#pragma unroll
      for (int r = 0; r < 4; r++) {
        float ss = 0.f;
#pragma unroll
        for (int nf = 0; nf < 4; nf++) ss += acc[mf][nf][r] * acc[mf][nf][r];
        ss += __shfl_xor(ss, 1); ss += __shfl_xor(ss, 2);
        ss += __shfl_xor(ss, 4); ss += __shfl_xor(ss, 8);
        float nrm = fmaxf(sqrtf(ss), 1e-12f);
        float f = (sec == 0 ? LOG2E : 8.0f) / nrm;
#pragma unroll
        for (int nf = 0; nf < 4; nf++) acc[mf][nf][r] *= f;
      }
    }
    int rbase = bm + wr4 * 64 + mf * 16 + 4 * g;
#pragma unroll
    for (int r = 0; r < 4; r++) {
      int row = rbase + r;
      int b = row >> 11, tok = row & 2047;
      int bh = b * NH + head;
#pragma unroll
      for (int nf = 0; nf < 4; nf++) {
        int d = nf * 16 + l15;
        u16 val = f2bf(acc[mf][nf][r] * gv[nf]);
        if (sec == 0)      Qn[((size_t)bh * SL + tok) * HD + d] = val;
        else if (sec == 1) Kn[((size_t)bh * SL + tok) * HD + d] = val;
        else               Vt[((size_t)bh * HD + d) * SL + tok] = val;
      }
    }
  }
}

// ---------------- GEMM2: out = hm @ woutT^T + b_out (fp32 out) ----------------
__global__ __launch_bounds__(512, 2) void k_gemm_out(
    const u16* __restrict__ A, const u16* __restrict__ Bt,
    const float* __restrict__ bias, float* __restrict__ out) {
  __shared__ __align__(16) char Lsh[3][49152];
  int bid = blockIdx.x;
  bid = (bid & 7) * 32 + (bid >> 3);               // XCD swizzle, 256 blocks
  const int bm = (bid / 8) * 256, bn = (bid % 8) * 128;
  const int tid = threadIdx.x, lane = tid & 63, w = tid >> 6;
  const int l15 = lane & 15, g = lane >> 4;
  const int wr4 = w >> 1, wc2 = w & 1;

  const int rA  = tid >> 3;
  const int scb = ((tid & 7) << 4) ^ ((rA & 7) << 4);
  const char* Ab = (const char*)A + (size_t)(bm + rA) * 2048 + scb;
  const char* Bb = (const char*)Bt + (size_t)(bn + rA) * 2048 + scb;
  const int wb   = w << 10;
  const int aoff = (wr4 * 64 + l15) * 128;
  const int boff = 32768 + (wc2 * 64 + l15) * 128;
  const int cx0  = (g ^ (l15 & 7)) << 4;

  f32x4 acc[4][4];
#pragma unroll
  for (int i = 0; i < 4; i++)
#pragma unroll
    for (int j = 0; j < 4; j++) acc[i][j] = f32x4{0.f, 0.f, 0.f, 0.f};

  gemm_mainloop(Ab, Bb, (char*)Lsh, wb, aoff, boff, cx0, acc);

  float bv[4];
#pragma unroll
  for (int nf = 0; nf < 4; nf++) bv[nf] = bias[bn + wc2 * 64 + nf * 16 + l15];
#pragma unroll
  for (int mf = 0; mf < 4; mf++)
#pragma unroll
    for (int r = 0; r < 4; r++) {
      int row = bm + wr4 * 64 + mf * 16 + 4 * g + r;
#pragma unroll
      for (int nf = 0; nf < 4; nf++)
        out[(size_t)row * CIN + bn + wc2 * 64 + nf * 16 + l15] =
            acc[mf][nf][r] + bv[nf];
    }
}

// ---------------- flash attention: 8 waves x 32 q, static-max softmax ----------------
// Static per-head bound M >= all scores (exp2 domain) folded into the QK MFMA
// accumulator init (-M): no max tracking, no rescale, no branches. Uniform
// scaling 2^(m_row-M) cancels in the final 1/l normalization exactly.
__global__ __launch_bounds__(512) void k_attn(const u16* __restrict__ Qn,
                                              const u16* __restrict__ Kn,
                                              const u16* __restrict__ Vt,
                                              const float* __restrict__ bnd,
                                              u16* __restrict__ hm) {
  __shared__ __align__(16) char KL[2][8192];
  __shared__ __align__(16) char VL[2][8192];
  const int bh = blockIdx.x & 63, qb = blockIdx.x >> 6;   // qb 0..7
  const int tid = threadIdx.x, w = tid >> 6, lane = tid & 63;
  const int l31 = lane & 31, h = lane >> 5;
  const int qr0 = qb * 256 + w * 32;
  const float negM = -bnd[bh & 15];

  // ---- staging source addresses (per thread), pre-swizzled ----
  const int sr  = tid >> 3;                                  // 0..63 rows
  const int scb = ((tid & 7) << 4) ^ ((sr & 7) << 4);        // swizzled col-byte
  const char* kst = (const char*)(Kn + (size_t)bh * SL * HD) + (size_t)sr * 128 + scb;
  const char* vst = (const char*)(Vt + (size_t)bh * HD * SL) + (size_t)sr * 4096 + scb;
  char* kl0 = KL[0] + (w << 10);
  char* vl0 = VL[0] + (w << 10);
  char* kl1 = KL[1] + (w << 10);
  char* vl1 = VL[1] + (w << 10);

  // ---- Q B-fragments (once): lane holds Q[qr0+l31][ks*16 + 8h + j] ----
  const u16* Qb = Qn + ((size_t)bh * SL + qr0 + l31) * HD + 8 * h;
  s16x8 qf[4];
#pragma unroll
  for (int ks = 0; ks < 4; ks++) qf[ks] = *(const s16x8*)(Qb + ks * 16);

  // lane LDS read base byte offset (within a 32-row half tile)
  const int lb = l31 * 128 + ((h << 4) ^ ((l31 & 7) << 4));

  f32x16 o0, o1;
#pragma unroll
  for (int i = 0; i < 16; i++) { o0[i] = 0.f; o1[i] = 0.f; }
  float lr = 0.f;   // this lane's half-row partial sum

  // prologue: stage kb=0 into buf 0
  gload_lds16(kst, kl0);
  gload_lds16(vst, vl0);
  __syncthreads();

  for (int it = 0; it < 32; ++it) {
    const char* KB = (it & 1) ? KL[1] : KL[0];
    const char* VB = (it & 1) ? VL[1] : VL[0];
    if (it < 31) {                                   // prefetch next tile
      const size_t ko = (size_t)(it + 1) << 13;      // 64 rows * 128 B
      const size_t vo = (size_t)(it + 1) << 7;       // 64 toks * 2 B
      gload_lds16(kst + ko, (it & 1) ? kl0 : kl1);
      gload_lds16(vst + vo, (it & 1) ? vl0 : vl1);
    }

    // ---- QK^T (swapped), accumulator pre-loaded with -M ----
    f32x16 s0, s1;
#pragma unroll
    for (int i = 0; i < 16; i++) { s0[i] = negM; s1[i] = negM; }
    __builtin_amdgcn_s_setprio(1);
#pragma unroll
    for (int ks = 0; ks < 4; ks++) {
      const s16x8 ka  = *(const s16x8*)(KB + (lb ^ (ks << 5)));
      const s16x8 kb2 = *(const s16x8*)(KB + 4096 + (lb ^ (ks << 5)));
      s0 = mfma32(ka, qf[ks], s0);
      s1 = mfma32(kb2, qf[ks], s1);
    }
    __builtin_amdgcn_s_setprio(0);

    // ---- softmax numerators: p = exp2(s - M), fully parallel ----
#pragma unroll
    for (int i = 0; i < 16; i++) s0[i] = __builtin_amdgcn_exp2f(s0[i]);
#pragma unroll
    for (int i = 0; i < 16; i++) s1[i] = __builtin_amdgcn_exp2f(s1[i]);
    float sm8[8];
#pragma unroll
    for (int i = 0; i < 8; i++)
      sm8[i] = (s0[i] + s0[i + 8]) + (s1[i] + s1[i + 8]);
    lr += ((sm8[0] + sm8[1]) + (sm8[2] + sm8[3])) +
          ((sm8[4] + sm8[5]) + (sm8[6] + sm8[7]));

    // ---- P -> bf16 B-fragments (T12), PV ----
    union PBu { unsigned u[4]; s16x8 v; } pb;
#define MK_PB(SV, B)                              \
    {                                             \
      unsigned a0 = cvtpk(SV[B + 0], SV[B + 1]);  \
      unsigned c0 = cvtpk(SV[B + 4], SV[B + 5]);  \
      plswap(a0, c0);                             \
      unsigned a1 = cvtpk(SV[B + 2], SV[B + 3]);  \
      unsigned c1 = cvtpk(SV[B + 6], SV[B + 7]);  \
      plswap(a1, c1);                             \
      pb.u[0] = a0; pb.u[1] = a1; pb.u[2] = c0; pb.u[3] = c1; \
    }
#define PV_STEP(KS)                                            \
    {                                                          \
      const s16x8 va = *(const s16x8*)(VB + (lb ^ (KS << 5))); \
      const s16x8 vb = *(const s16x8*)(VB + 4096 + (lb ^ (KS << 5))); \
      __builtin_amdgcn_s_setprio(1);                           \
      o0 = mfma32(va, pb.v, o0);                               \
      o1 = mfma32(vb, pb.v, o1);                               \
      __builtin_amdgcn_s_setprio(0);                           \
    }
    MK_PB(s0, 0) PV_STEP(0)
    MK_PB(s0, 8) PV_STEP(1)
    MK_PB(s1, 0) PV_STEP(2)
    MK_PB(s1, 8) PV_STEP(3)
#undef MK_PB
#undef PV_STEP

    __syncthreads();   // drains vmcnt: next buffer staged; this buffer free
  }

  // ---- epilogue: combine half-row sums, normalize, store ----
  const float ltot = lr + __shfl_xor(lr, 32);
  const float inv = 1.f / ltot;
  const int bq = bh >> 4, hh = bh & 15;
  u16* hb = hm + ((size_t)bq * SL + qr0 + l31) * CIN + hh * HD;
#pragma unroll
  for (int rg = 0; rg < 4; rg++) {
    const int d0 = 8 * rg + 4 * h;
    unsigned lo = cvtpk(o0[4 * rg + 0] * inv, o0[4 * rg + 1] * inv);
    unsigned hi = cvtpk(o0[4 * rg + 2] * inv, o0[4 * rg + 3] * inv);
    *(unsigned long long*)(hb + d0) =
        (unsigned long long)lo | ((unsigned long long)hi << 32);
    unsigned lo1 = cvtpk(o1[4 * rg + 0] * inv, o1[4 * rg + 1] * inv);
    unsigned hi1 = cvtpk(o1[4 * rg + 2] * inv, o1[4 * rg + 3] * inv);
    *(unsigned long long*)(hb + 32 + d0) =
        (unsigned long long)lo1 | ((unsigned long long)hi1 << 32);
  }
}

extern "C" void kernel_launch(void* const* d_in, const int* in_sizes, int n_in,
                              void* d_out, int out_size, void* d_ws, size_t ws_size,
                              hipStream_t stream) {
  const float* x    = (const float*)d_in[0];
  const float* Wqkv = (const float*)d_in[1];
  const float* bqkv = (const float*)d_in[2];
  const float* gq   = (const float*)d_in[3];
  const float* gk   = (const float*)d_in[4];
  const float* Wout = (const float*)d_in[5];
  const float* bout = (const float*)d_in[6];
  float* out = (float*)d_out;

  char* ws = (char*)d_ws;
  u16* xb  = (u16*)(ws);                       // 16,777,216 B
  u16* wqT = (u16*)(ws + 16777216);            //  6,291,456 B
  u16* woT = (u16*)(ws + 23068672);            //  2,097,152 B
  u16* Qn  = (u16*)(ws + 25165824);            // 16,777,216 B
  u16* Kn  = (u16*)(ws + 41943040);            // 16,777,216 B
  u16* Vt  = (u16*)(ws + 58720256);            // 16,777,216 B
  u16* hm  = (u16*)(ws + 75497472);            // 16,777,216 B  (end: 92,274,688)
  float* bnd = (float*)(ws + 92274688);        // 64 B

  k_prep<<<2049, 256, 0, stream>>>(x, xb, Wqkv, wqT, Wout, woT, gq, gk, bnd);
  k_gemm_qkv<<<(TOK / 256) * (C3 / 128), 512, 0, stream>>>(xb, wqT, bqkv, gq, gk, Qn, Kn, Vt);
  k_attn<<<BH * (SL / 256), 512, 0, stream>>>(Qn, Kn, Vt, bnd, hm);
  k_gemm_out<<<(TOK / 256) * (CIN / 128), 512, 0, stream>>>(hm, woT, bout, out);
}

// Round 15
// 196.879 us; speedup vs baseline: 1.9763x; 1.0134x over previous
//
#include <hip/hip_runtime.h>

using u16 = unsigned short;

typedef float  f32x4  __attribute__((ext_vector_type(4)));
typedef float  f32x16 __attribute__((ext_vector_type(16)));
typedef __bf16 bf16x8 __attribute__((ext_vector_type(8)));
typedef short  s16x8  __attribute__((ext_vector_type(8)));

#define DEVI __device__ __forceinline__

constexpr int TOK = 8192;    // N = B*L
constexpr int CIN = 1024;    // C
constexpr int C3  = 3072;    // 3C
constexpr int NH  = 16;
constexpr int HD  = 64;
constexpr int SL  = 2048;
constexpr int BH  = 64;      // B*H

constexpr float LOG2E = 1.4426950408889634f;

DEVI u16 f2bf(float x) {
  unsigned u = __builtin_bit_cast(unsigned, x);
  u += 0x7FFFu + ((u >> 16) & 1u);   // round-to-nearest-even
  return (u16)(u >> 16);
}

DEVI f32x4 mfma16(s16x8 a, s16x8 b, f32x4 c) {
  return __builtin_amdgcn_mfma_f32_16x16x32_bf16(
      __builtin_bit_cast(bf16x8, a), __builtin_bit_cast(bf16x8, b), c, 0, 0, 0);
}

DEVI f32x16 mfma32(s16x8 a, s16x8 b, f32x16 c) {
  return __builtin_amdgcn_mfma_f32_32x32x16_bf16(
      __builtin_bit_cast(bf16x8, a), __builtin_bit_cast(bf16x8, b), c, 0, 0, 0);
}

DEVI void gload_lds16(const void* g, void* l) {
  __builtin_amdgcn_global_load_lds(
      (const __attribute__((address_space(1))) unsigned int*)g,
      (__attribute__((address_space(3))) unsigned int*)l, 16, 0, 0);
}

DEVI unsigned cvtpk(float lo, float hi) {
  unsigned r;
  asm("v_cvt_pk_bf16_f32 %0, %1, %2" : "=v"(r) : "v"(lo), "v"(hi));
  return r;
}

DEVI void plswap(unsigned& a, unsigned& b) {
  asm("v_permlane32_swap_b32 %0, %1" : "+v"(a), "+v"(b));
}

// ---------------- merged preprocessing: cvt_x | transpose Wqkv | transpose Wout | bound ----
DEVI void do_transpose(const float* __restrict__ in, u16* __restrict__ out,
                       int R, int C, int blk, int tid, u16 (*t)[72]) {
  int rt = R >> 6;
  int tr = (blk % rt) << 6;
  int tc = (blk / rt) << 6;
#pragma unroll
  for (int k2 = 0; k2 < 16; k2++) {
    int idx = k2 * 256 + tid;
    int r = idx >> 6, c = idx & 63;
    t[r][c] = f2bf(in[(size_t)(tr + r) * C + tc + c]);
  }
  __syncthreads();
#pragma unroll
  for (int k2 = 0; k2 < 16; k2++) {
    int idx = k2 * 256 + tid;
    int r = idx >> 6, c = idx & 63;
    out[(size_t)(tc + r) * R + tr + c] = t[c][r];
  }
}

__global__ __launch_bounds__(256) void k_prep(
    const float* __restrict__ x, u16* __restrict__ xb,
    const float* __restrict__ Wqkv, u16* __restrict__ wqT,
    const float* __restrict__ Wout, u16* __restrict__ woT,
    const float* __restrict__ gq, const float* __restrict__ gk,
    float* __restrict__ bnd) {
  __shared__ u16 t[64][72];
  const int bid = blockIdx.x, tid = threadIdx.x;
  if (bid < 1024) {
    const int total = TOK * CIN / 4;
    for (int i = bid * 256 + tid; i < total; i += 1024 * 256) {
      float4 v = ((const float4*)x)[i];
      ushort4 o;
      o.x = f2bf(v.x); o.y = f2bf(v.y); o.z = f2bf(v.z); o.w = f2bf(v.w);
      ((ushort4*)xb)[i] = o;
    }
  } else if (bid < 1024 + 768) {
    do_transpose(Wqkv, wqT, 1024, 3072, bid - 1024, tid, t);
  } else if (bid < 1024 + 768 + 256) {
    do_transpose(Wout, woT, 1024, 1024, bid - 1792, tid, t);
  } else {
    const int h = tid >> 4, s = tid & 15;
    float mv = 0.f;
#pragma unroll
    for (int j = 0; j < 4; j++) {
      int d = s * 4 + j;
      mv = fmaxf(mv, fabsf(gq[h * 64 + d] * gk[h * 64 + d]));
    }
    mv = fmaxf(mv, __shfl_xor(mv, 1));
    mv = fmaxf(mv, __shfl_xor(mv, 2));
    mv = fmaxf(mv, __shfl_xor(mv, 4));
    mv = fmaxf(mv, __shfl_xor(mv, 8));
    if (s == 0) bnd[h] = 8.0f * LOG2E * mv;
  }
}

// ======== shared GEMM main loop: BM=256 BN=128 BK=64, ring-3, counted vmcnt ========
// (R10 configuration: 1 block/CU, write-combining-safe, best measured)
#define STAGE6(BUF, KT)                                                  \
  { char* Ld = L + (BUF) * 49152;                                        \
    const size_t ko = (size_t)(KT) * 128;                                \
    gload_lds16(Ab + ko,          Ld + wb);                              \
    gload_lds16(Ab + ko + 131072, Ld + 8192 + wb);                       \
    gload_lds16(Ab + ko + 262144, Ld + 16384 + wb);                      \
    gload_lds16(Ab + ko + 393216, Ld + 24576 + wb);                      \
    gload_lds16(Bb + ko,          Ld + 32768 + wb);                      \
    gload_lds16(Bb + ko + 131072, Ld + 40960 + wb); }

#define KBODY(KT, DOSTAGE, VMSTR)                                        \
  {                                                                      \
    if (DOSTAGE) STAGE6(((KT) + 2) % 3, (KT) + 2)                        \
    asm volatile("s_waitcnt " VMSTR ::: "memory");                       \
    __builtin_amdgcn_s_barrier();                                        \
    const char* Lb = L + ((KT) % 3) * 49152;                             \
    s16x8 af[4][2], bfr[4][2];                                           \
    _Pragma("unroll")                                                    \
    for (int mf = 0; mf < 4; mf++) {                                     \
      af[mf][0] = *(const s16x8*)(Lb + aoff + mf * 2048 + cx0);          \
      af[mf][1] = *(const s16x8*)(Lb + aoff + mf * 2048 + (cx0 ^ 64));   \
    }                                                                    \
    _Pragma("unroll")                                                    \
    for (int nf = 0; nf < 4; nf++) {                                     \
      bfr[nf][0] = *(const s16x8*)(Lb + boff + nf * 2048 + cx0);         \
      bfr[nf][1] = *(const s16x8*)(Lb + boff + nf * 2048 + (cx0 ^ 64));  \
    }                                                                    \
    __builtin_amdgcn_s_setprio(1);                                       \
    _Pragma("unroll")                                                    \
    for (int ks = 0; ks < 2; ks++)                                       \
      _Pragma("unroll")                                                  \
      for (int mf = 0; mf < 4; mf++)                                     \
        _Pragma("unroll")                                                \
        for (int nf = 0; nf < 4; nf++)                                   \
          acc[mf][nf] = mfma16(af[mf][ks], bfr[nf][ks], acc[mf][nf]);    \
    __builtin_amdgcn_s_setprio(0);                                       \
    __builtin_amdgcn_s_barrier();                                        \
  }

DEVI void gemm_mainloop(const char* Ab, const char* Bb, char* L,
                        int wb, int aoff, int boff, int cx0,
                        f32x4 (&acc)[4][4]) {
  STAGE6(0, 0)
  STAGE6(1, 1)
#pragma unroll
  for (int kt = 0; kt < 14; ++kt) KBODY(kt, 1, "vmcnt(12)")
  KBODY(14, 0, "vmcnt(6)")
  KBODY(15, 0, "vmcnt(0)")
}

// ---------------- GEMM1: qkv = xb @ wqkvT^T, fused bias+norm+repack ----------------
__global__ __launch_bounds__(512, 2) void k_gemm_qkv(
    const u16* __restrict__ A, const u16* __restrict__ Bt,
    const float* __restrict__ bias, const float* __restrict__ gq,
    const float* __restrict__ gk,
    u16* __restrict__ Qn, u16* __restrict__ Kn, u16* __restrict__ Vt) {
  __shared__ __align__(16) char Lsh[3][49152];
  int bid = blockIdx.x;
  bid = (bid & 7) * 96 + (bid >> 3);               // XCD swizzle, 768 blocks
  const int bm = (bid / 24) * 256, bn = (bid % 24) * 128;
  const int tid = threadIdx.x, lane = tid & 63, w = tid >> 6;
  const int l15 = lane & 15, g = lane >> 4;
  const int wr4 = w >> 1, wc2 = w & 1;

  const int rA  = tid >> 3;
  const int scb = ((tid & 7) << 4) ^ ((rA & 7) << 4);
  const char* Ab = (const char*)A + (size_t)(bm + rA) * 2048 + scb;
  const char* Bb = (const char*)Bt + (size_t)(bn + rA) * 2048 + scb;
  const int wb   = w << 10;
  const int aoff = (wr4 * 64 + l15) * 128;
  const int boff = 32768 + (wc2 * 64 + l15) * 128;
  const int cx0  = (g ^ (l15 & 7)) << 4;

  f32x4 acc[4][4];
#pragma unroll
  for (int i = 0; i < 4; i++)
#pragma unroll
    for (int j = 0; j < 4; j++) acc[i][j] = f32x4{0.f, 0.f, 0.f, 0.f};

  gemm_mainloop(Ab, Bb, (char*)Lsh, wb, aoff, boff, cx0, acc);

  // epilogue: bias, per-head L2 norm for q/k (64 cols == one head), repack
  const int c0 = bn + wc2 * 64;       // 64-aligned
  const int sec = c0 >> 10;           // 0=q 1=k 2=v
  const int head = (c0 & 1023) >> 6;
  float bv[4], gv[4];
#pragma unroll
  for (int nf = 0; nf < 4; nf++) {
    bv[nf] = bias[c0 + nf * 16 + l15];
    gv[nf] = 1.f;
    if (sec == 0) gv[nf] = gq[head * 64 + nf * 16 + l15];
    if (sec == 1) gv[nf] = gk[head * 64 + nf * 16 + l15];
  }
#pragma unroll
  for (int mf = 0; mf < 4; mf++) {
#pragma unroll
    for (int nf = 0; nf < 4; nf++)
#pragma unroll
      for (int r = 0; r < 4; r++) acc[mf][nf][r] += bv[nf];
    if (sec < 2) {
#pragma unroll
      for (int r = 0; r < 4; r++) {
        float ss = 0.f;
#pragma unroll
        for (int nf = 0; nf < 4; nf++) ss += acc[mf][nf][r] * acc[mf][nf][r];
        ss += __shfl_xor(ss, 1); ss += __shfl_xor(ss, 2);
        ss += __shfl_xor(ss, 4); ss += __shfl_xor(ss, 8);
        float nrm = fmaxf(sqrtf(ss), 1e-12f);
        float f = (sec == 0 ? LOG2E : 8.0f) / nrm;
#pragma unroll
        for (int nf = 0; nf < 4; nf++) acc[mf][nf][r] *= f;
      }
    }
    int rbase = bm + wr4 * 64 + mf * 16 + 4 * g;
#pragma unroll
    for (int r = 0; r < 4; r++) {
      int row = rbase + r;
      int b = row >> 11, tok = row & 2047;
      int bh = b * NH + head;
#pragma unroll
      for (int nf = 0; nf < 4; nf++) {
        int d = nf * 16 + l15;
        u16 val = f2bf(acc[mf][nf][r] * gv[nf]);
        if (sec == 0)      Qn[((size_t)bh * SL + tok) * HD + d] = val;
        else if (sec == 1) Kn[((size_t)bh * SL + tok) * HD + d] = val;
        else               Vt[((size_t)bh * HD + d) * SL + tok] = val;
      }
    }
  }
}

// ---------------- GEMM2: out = hm @ woutT^T + b_out (fp32 out) ----------------
__global__ __launch_bounds__(512, 2) void k_gemm_out(
    const u16* __restrict__ A, const u16* __restrict__ Bt,
    const float* __restrict__ bias, float* __restrict__ out) {
  __shared__ __align__(16) char Lsh[3][49152];
  int bid = blockIdx.x;
  bid = (bid & 7) * 32 + (bid >> 3);               // XCD swizzle, 256 blocks
  const int bm = (bid / 8) * 256, bn = (bid % 8) * 128;
  const int tid = threadIdx.x, lane = tid & 63, w = tid >> 6;
  const int l15 = lane & 15, g = lane >> 4;
  const int wr4 = w >> 1, wc2 = w & 1;

  const int rA  = tid >> 3;
  const int scb = ((tid & 7) << 4) ^ ((rA & 7) << 4);
  const char* Ab = (const char*)A + (size_t)(bm + rA) * 2048 + scb;
  const char* Bb = (const char*)Bt + (size_t)(bn + rA) * 2048 + scb;
  const int wb   = w << 10;
  const int aoff = (wr4 * 64 + l15) * 128;
  const int boff = 32768 + (wc2 * 64 + l15) * 128;
  const int cx0  = (g ^ (l15 & 7)) << 4;

  f32x4 acc[4][4];
#pragma unroll
  for (int i = 0; i < 4; i++)
#pragma unroll
    for (int j = 0; j < 4; j++) acc[i][j] = f32x4{0.f, 0.f, 0.f, 0.f};

  gemm_mainloop(Ab, Bb, (char*)Lsh, wb, aoff, boff, cx0, acc);

  float bv[4];
#pragma unroll
  for (int nf = 0; nf < 4; nf++) bv[nf] = bias[bn + wc2 * 64 + nf * 16 + l15];
#pragma unroll
  for (int mf = 0; mf < 4; mf++)
#pragma unroll
    for (int r = 0; r < 4; r++) {
      int row = bm + wr4 * 64 + mf * 16 + 4 * g + r;
#pragma unroll
      for (int nf = 0; nf < 4; nf++)
        out[(size_t)row * CIN + bn + wc2 * 64 + nf * 16 + l15] =
            acc[mf][nf][r] + bv[nf];
    }
}

// ---------------- flash attention: 8 waves x 32 q, static-max softmax ----------------
// Ring-3 K/V staging with COUNTED vmcnt (GEMM-proven pattern): stage tile t+2
// each iter; vmcnt(4) keeps t+1/t+2's loads in flight (never drains in steady
// state); 2 raw s_barriers/iter replace the __syncthreads full drain.
__global__ __launch_bounds__(512) void k_attn(const u16* __restrict__ Qn,
                                              const u16* __restrict__ Kn,
                                              const u16* __restrict__ Vt,
                                              const float* __restrict__ bnd,
                                              u16* __restrict__ hm) {
  __shared__ __align__(16) char KL[3][8192];
  __shared__ __align__(16) char VL[3][8192];
  const int bh = blockIdx.x & 63, qb = blockIdx.x >> 6;   // qb 0..7
  const int tid = threadIdx.x, w = tid >> 6, lane = tid & 63;
  const int l31 = lane & 31, h = lane >> 5;
  const int qr0 = qb * 256 + w * 32;
  const float negM = -bnd[bh & 15];

  // ---- staging source addresses (per thread), pre-swizzled ----
  const int sr  = tid >> 3;                                  // 0..63 rows
  const int scb = ((tid & 7) << 4) ^ ((sr & 7) << 4);        // swizzled col-byte
  const char* kst = (const char*)(Kn + (size_t)bh * SL * HD) + (size_t)sr * 128 + scb;
  const char* vst = (const char*)(Vt + (size_t)bh * HD * SL) + (size_t)sr * 4096 + scb;
  const int kwoff = w << 10;

  // ---- Q B-fragments (once): lane holds Q[qr0+l31][ks*16 + 8h + j] ----
  const u16* Qb = Qn + ((size_t)bh * SL + qr0 + l31) * HD + 8 * h;
  s16x8 qf[4];
#pragma unroll
  for (int ks = 0; ks < 4; ks++) qf[ks] = *(const s16x8*)(Qb + ks * 16);

  // lane LDS read base byte offset (within a 32-row half tile)
  const int lb = l31 * 128 + ((h << 4) ^ ((l31 & 7) << 4));

  f32x16 o0, o1;
#pragma unroll
  for (int i = 0; i < 16; i++) { o0[i] = 0.f; o1[i] = 0.f; }
  float lr = 0.f;   // this lane's half-row partial sum

#define ATT_STAGE(SLOT, T)                                          \
  { gload_lds16(kst + ((size_t)(T) << 13), KL[SLOT] + kwoff);       \
    gload_lds16(vst + ((size_t)(T) << 7),  VL[SLOT] + kwoff); }

#define ATT_BODY(T, DOSTAGE, VMSTR)                                           \
  {                                                                           \
    if (DOSTAGE) ATT_STAGE(((T) + 2) % 3, (T) + 2)                            \
    asm volatile("s_waitcnt " VMSTR ::: "memory");                            \
    __builtin_amdgcn_s_barrier();                                             \
    const char* KB = KL[(T) % 3];                                             \
    const char* VB = VL[(T) % 3];                                             \
    f32x16 s0, s1;                                                            \
    _Pragma("unroll")                                                         \
    for (int i = 0; i < 16; i++) { s0[i] = negM; s1[i] = negM; }              \
    __builtin_amdgcn_s_setprio(1);                                            \
    _Pragma("unroll")                                                         \
    for (int ks = 0; ks < 4; ks++) {                                          \
      const s16x8 ka  = *(const s16x8*)(KB + (lb ^ (ks << 5)));               \
      const s16x8 kb2 = *(const s16x8*)(KB + 4096 + (lb ^ (ks << 5)));        \
      s0 = mfma32(ka, qf[ks], s0);                                            \
      s1 = mfma32(kb2, qf[ks], s1);                                           \
    }                                                                         \
    __builtin_amdgcn_s_setprio(0);                                            \
    _Pragma("unroll")                                                         \
    for (int i = 0; i < 16; i++) s0[i] = __builtin_amdgcn_exp2f(s0[i]);       \
    _Pragma("unroll")                                                         \
    for (int i = 0; i < 16; i++) s1[i] = __builtin_amdgcn_exp2f(s1[i]);       \
    float sm8[8];                                                             \
    _Pragma("unroll")                                                         \
    for (int i = 0; i < 8; i++)                                               \
      sm8[i] = (s0[i] + s0[i + 8]) + (s1[i] + s1[i + 8]);                     \
    lr += ((sm8[0] + sm8[1]) + (sm8[2] + sm8[3])) +                           \
          ((sm8[4] + sm8[5]) + (sm8[6] + sm8[7]));                            \
    union PBu { unsigned u[4]; s16x8 v; } pb;                                 \
    MK_PB(s0, 0) PV_STEP(0)                                                   \
    MK_PB(s0, 8) PV_STEP(1)                                                   \
    MK_PB(s1, 0) PV_STEP(2)                                                   \
    MK_PB(s1, 8) PV_STEP(3)                                                   \
    __builtin_amdgcn_s_barrier();                                             \
  }

#define MK_PB(SV, B)                              \
    {                                             \
      unsigned a0 = cvtpk(SV[B + 0], SV[B + 1]);  \
      unsigned c0 = cvtpk(SV[B + 4], SV[B + 5]);  \
      plswap(a0, c0);                             \
      unsigned a1 = cvtpk(SV[B + 2], SV[B + 3]);  \
      unsigned c1 = cvtpk(SV[B + 6], SV[B + 7]);  \
      plswap(a1, c1);                             \
      pb.u[0] = a0; pb.u[1] = a1; pb.u[2] = c0; pb.u[3] = c1; \
    }
#define PV_STEP(KS)                                            \
    {                                                          \
      const s16x8 va = *(const s16x8*)(VB + (lb ^ (KS << 5))); \
      const s16x8 vb = *(const s16x8*)(VB + 4096 + (lb ^ (KS << 5))); \
      __builtin_amdgcn_s_setprio(1);                           \
      o0 = mfma32(va, pb.v, o0);                               \
      o1 = mfma32(vb, pb.v, o1);                               \
      __builtin_amdgcn_s_setprio(0);                           \
    }

  // prologue: stage tiles 0 and 1 (4 loads in flight)
  ATT_STAGE(0, 0)
  ATT_STAGE(1, 1)
#pragma unroll 3
  for (int t = 0; t < 30; ++t) ATT_BODY(t, 1, "vmcnt(4)")
  ATT_BODY(30, 0, "vmcnt(2)")
  ATT_BODY(31, 0, "vmcnt(0)")
#undef ATT_STAGE
#undef ATT_BODY
#undef MK_PB
#undef PV_STEP

  // ---- epilogue: combine half-row sums, normalize, store ----
  const float ltot = lr + __shfl_xor(lr, 32);
  const float inv = 1.f / ltot;
  const int bq = bh >> 4, hh = bh & 15;
  u16* hb = hm + ((size_t)bq * SL + qr0 + l31) * CIN + hh * HD;
#pragma unroll
  for (int rg = 0; rg < 4; rg++) {
    const int d0 = 8 * rg + 4 * h;
    unsigned lo = cvtpk(o0[4 * rg + 0] * inv, o0[4 * rg + 1] * inv);
    unsigned hi = cvtpk(o0[4 * rg + 2] * inv, o0[4 * rg + 3] * inv);
    *(unsigned long long*)(hb + d0) =
        (unsigned long long)lo | ((unsigned long long)hi << 32);
    unsigned lo1 = cvtpk(o1[4 * rg + 0] * inv, o1[4 * rg + 1] * inv);
    unsigned hi1 = cvtpk(o1[4 * rg + 2] * inv, o1[4 * rg + 3] * inv);
    *(unsigned long long*)(hb + 32 + d0) =
        (unsigned long long)lo1 | ((unsigned long long)hi1 << 32);
  }
}

extern "C" void kernel_launch(void* const* d_in, const int* in_sizes, int n_in,
                              void* d_out, int out_size, void* d_ws, size_t ws_size,
                              hipStream_t stream) {
  const float* x    = (const float*)d_in[0];
  const float* Wqkv = (const float*)d_in[1];
  const float* bqkv = (const float*)d_in[2];
  const float* gq   = (const float*)d_in[3];
  const float* gk   = (const float*)d_in[4];
  const float* Wout = (const float*)d_in[5];
  const float* bout = (const float*)d_in[6];
  float* out = (float*)d_out;

  char* ws = (char*)d_ws;
  u16* xb  = (u16*)(ws);                       // 16,777,216 B
  u16* wqT = (u16*)(ws + 16777216);            //  6,291,456 B
  u16* woT = (u16*)(ws + 23068672);            //  2,097,152 B
  u16* Qn  = (u16*)(ws + 25165824);            // 16,777,216 B
  u16* Kn  = (u16*)(ws + 41943040);            // 16,777,216 B
  u16* Vt  = (u16*)(ws + 58720256);            // 16,777,216 B
  u16* hm  = (u16*)(ws + 75497472);            // 16,777,216 B  (end: 92,274,688)
  float* bnd = (float*)(ws + 92274688);        // 64 B

  k_prep<<<2049, 256, 0, stream>>>(x, xb, Wqkv, wqT, Wout, woT, gq, gk, bnd);
  k_gemm_qkv<<<(TOK / 256) * (C3 / 128), 512, 0, stream>>>(xb, wqT, bqkv, gq, gk, Qn, Kn, Vt);
  k_attn<<<BH * (SL / 256), 512, 0, stream>>>(Qn, Kn, Vt, bnd, hm);
  k_gemm_out<<<(TOK / 256) * (CIN / 128), 512, 0, stream>>>(hm, woT, bout, out);
}